// Round 4
// baseline (10020.445 us; speedup 1.0000x reference)
//
#include <hip/hip_runtime.h>
#include <hip/hip_fp16.h>

#define BB 128
#define II 64
#define SS 2048
#define HH 128
#define GG 512   // 4*H
#define OO 64

typedef _Float16 f16x2 __attribute__((ext_vector_type(2)));
union F4H { float4 f4; f16x2 h[4]; };

__device__ __forceinline__ f16x2 pack2(float a, float b) {
    f16x2 r; r.x = (_Float16)a; r.y = (_Float16)b; return r;
}
__device__ __forceinline__ float dot2(f16x2 w, f16x2 v, float c) {
    return __builtin_amdgcn_fdot2(w, v, c, false);
}
__device__ __forceinline__ float sigm(float v) {
    return __builtin_amdgcn_rcpf(1.0f + __expf(-v));
}
__device__ __forceinline__ float tanh_f(float v) {
    float a = fabsf(v);
    float e = __expf(-2.0f * a);
    float r = (1.0f - e) * __builtin_amdgcn_rcpf(1.0f + e);
    return v < 0.0f ? -r : r;
}

// One block per batch element, 1024 threads (16 waves). Lane pair (2k,2k+1)
// owns gate column k with the K-dimension split across the pair:
//   even lane (s=0): x[0:32)@Wx_out + h[0:64)@Wh_out ; x_in@Wx_in
//   odd  lane (s=1): x[32:64)@Wx_out + h[64:128)@Wh_out ; h_in@Wh_in
// Per-thread register weights: 32 (Wh_out half) + 64 (Wx_in or Wh_in) = 96
// f16x2 VGPRs -> fits the 128-VGPR cap that flat-wg=1024 implies. Rounds
// 1-3 showed the allocator never exceeds 128 VGPRs: 192-reg designs get
// spilled (R3: 103 GB scratch reloads @17.5 TB/s L2/L3 = the whole runtime)
// or rematerialized (R2). Partials combine via shfl_xor(1) - no barrier.
__global__ void __launch_bounds__(1024)
nlstm_scan(
    const float* __restrict__ x,
    const float* __restrict__ Wx_out, const float* __restrict__ Wh_out,
    const float* __restrict__ b_out,
    const float* __restrict__ Wx_in, const float* __restrict__ Wh_in,
    const float* __restrict__ b_in,
    const float* __restrict__ W_lin, const float* __restrict__ b_lin,
    float* __restrict__ out)
{
    const int b   = blockIdx.x;
    const int j   = threadIdx.x;
    const int col = j >> 1;    // gate column 0..511
    const int s   = j & 1;     // K-split half within the lane pair

    // Wx_out fp16 chunk-major: chunk c (k=8c..8c+8) of column n at wxf[c*512+n]
    __shared__ __align__(16) float4 wxf[8 * 512];      // 64 KB
    // W_lin fp16 chunk-major padded: chunk c of row pn at wlf[c*66+pn]
    __shared__ __align__(16) float4 wlf[16 * 66];      // 16.9 KB
    __shared__ __align__(16) f16x2 xb[2][II / 2];      // x_t fp16, dbuf (8 chunks)
    __shared__ __align__(16) f16x2 hb[HH / 2];         // h fp16 (16 chunks)
    __shared__ __align__(16) f16x2 xih[HH];            // x_in (chunks 0-15) + h_in (16-31)
    __shared__ __align__(16) float cb[HH];             // outer cell fp32
    __shared__ __align__(16) float cnb[HH];            // inner cell fp32
    __shared__ __align__(16) float actO[GG];
    __shared__ __align__(16) float actI[GG];

    // ---- register-resident fp16 weights: 96 VGPRs/thread ----
    f16x2 who[32];   // Wh_out rows [64s, 64s+64) of column col
    f16x2 win[64];   // s==0: Wx_in col (all 128 rows); s==1: Wh_in col
    {
        const float* wp = Wh_out + (size_t)(64 * s) * GG + col;
#pragma unroll
        for (int m = 0; m < 32; ++m)
            who[m] = pack2(wp[(2 * m) * GG], wp[(2 * m + 1) * GG]);
        const float* vp = (s ? Wh_in : Wx_in) + col;
#pragma unroll
        for (int m = 0; m < 64; ++m)
            win[m] = pack2(vp[(2 * m) * GG], vp[(2 * m + 1) * GG]);
    }
    // Pin against rematerialization (spill risk is low: demand ~= budget).
#pragma unroll
    for (int m = 0; m < 32; ++m) {
        float t0 = __builtin_bit_cast(float, who[m]);
        asm volatile("" : "+v"(t0));
        who[m] = __builtin_bit_cast(f16x2, t0);
    }
#pragma unroll
    for (int m = 0; m < 64; ++m) {
        float t0 = __builtin_bit_cast(float, win[m]);
        asm volatile("" : "+v"(t0));
        win[m] = __builtin_bit_cast(f16x2, t0);
    }

    const float bo = b_out[col];
    const float bi = b_in[col];
    const int   pn = j >> 4;   // projection output row (0..63)
    const int   ps = j & 15;   // projection chunk (0..15)
    const float bl = b_lin[pn];

    // ---- stage Wx_out -> LDS fp16 (setup only) ----
    {
        const int half = j >> 9, n = j & 511;
#pragma unroll
        for (int q = 0; q < 4; ++q) {
            const int c = 4 * half + q;
            F4H u;
#pragma unroll
            for (int r = 0; r < 4; ++r)
                u.h[r] = pack2(Wx_out[(8 * c + 2 * r) * GG + n],
                               Wx_out[(8 * c + 2 * r + 1) * GG + n]);
            wxf[c * 512 + n] = u.f4;
        }
    }
    // ---- stage W_lin -> LDS fp16 (1024 chunks, 1 per thread) ----
    {
        const int c = j >> 6, n = j & 63;
        F4H u;
#pragma unroll
        for (int r = 0; r < 4; ++r)
            u.h[r] = pack2(W_lin[n * HH + 8 * c + 2 * r],
                           W_lin[n * HH + 8 * c + 2 * r + 1]);
        wlf[c * 66 + n] = u.f4;
    }

    const float* xrow = x + (size_t)b * II * SS;   // x[b,i,t] = xrow[i*SS + t]
    float* orow = out + (size_t)b * SS * OO;

    if (j < HH / 2) hb[j] = pack2(0.f, 0.f);
    if (j < HH) { cb[j] = 0.f; cnb[j] = 0.f; }
    if (j < II / 2)  // stage x for t=0
        xb[0][j] = pack2(xrow[(2 * j) * SS], xrow[(2 * j + 1) * SS]);
    __syncthreads();

    const float4* hb4 = (const float4*)hb;               // 16 chunks
    const float4* vin = (const float4*)xih + 16 * s;     // my inner operand

#pragma unroll 1
    for (int t = 0; t < SS; ++t) {
        const float4* xb4 = (const float4*)xb[t & 1];    // 8 chunks

        // ---- P1: outer gates (half-K per lane) ----
        float acc = 0.f;
#pragma unroll
        for (int q = 0; q < 4; ++q) {                    // x part: chunks 4s+q
            F4H xu; xu.f4 = xb4[4 * s + q];
            F4H wu; wu.f4 = wxf[(4 * s + q) * 512 + col];
            acc = dot2(wu.h[0], xu.h[0], acc);
            acc = dot2(wu.h[1], xu.h[1], acc);
            acc = dot2(wu.h[2], xu.h[2], acc);
            acc = dot2(wu.h[3], xu.h[3], acc);
        }
#pragma unroll
        for (int q = 0; q < 8; ++q) {                    // h part: chunks 8s+q
            F4H hu; hu.f4 = hb4[8 * s + q];
            acc = dot2(who[4 * q + 0], hu.h[0], acc);
            acc = dot2(who[4 * q + 1], hu.h[1], acc);
            acc = dot2(who[4 * q + 2], hu.h[2], acc);
            acc = dot2(who[4 * q + 3], hu.h[3], acc);
        }
        {
            const float tot = acc + __shfl_xor(acc, 1, 64) + bo;
            actO[col] = (col < 384) ? sigm(tot) : tanh_f(tot);  // both lanes write same value
        }
        __syncthreads();   // B1

        // ---- P2: form x_in / h_in; prefetch x for t+1 ----
        if (j < HH) {
            ((_Float16*)xih)[j] = (_Float16)(actO[j] * actO[384 + j]);       // x_in
        } else if (j < 2 * HH) {
            const int d = j - HH;
            ((_Float16*)xih)[HH + d] = (_Float16)(actO[HH + d] * cb[d]);     // h_in
        } else if (j >= 512 && j < 512 + II / 2 && t + 1 < SS) {
            const int m = j - 512;
            xb[(t + 1) & 1][m] = pack2(xrow[(2 * m) * SS + t + 1],
                                       xrow[(2 * m + 1) * SS + t + 1]);
        }
        __syncthreads();   // B2

        // ---- P3: inner gates (even lane: x_in@Wx_in, odd: h_in@Wh_in) ----
        float a2 = 0.f;
#pragma unroll
        for (int c = 0; c < 16; ++c) {
            F4H u; u.f4 = vin[c];
            a2 = dot2(win[4 * c + 0], u.h[0], a2);
            a2 = dot2(win[4 * c + 1], u.h[1], a2);
            a2 = dot2(win[4 * c + 2], u.h[2], a2);
            a2 = dot2(win[4 * c + 3], u.h[3], a2);
        }
        {
            const float tot = a2 + __shfl_xor(a2, 1, 64) + bi;
            actI[col] = (col < 384) ? sigm(tot) : tanh_f(tot);
        }
        __syncthreads();   // B3

        // ---- P4: state update (threads 0..127) ----
        if (j < HH) {
            const float cn_new = actI[HH + j] * cnb[j] + actI[j] * actI[384 + j];
            const float c_new  = actI[2 * HH + j] * tanh_f(cn_new);
            const float h_new  = actO[2 * HH + j] * tanh_f(c_new);
            cnb[j] = cn_new;
            cb[j]  = c_new;
            ((_Float16*)hb)[j] = (_Float16)h_new;
        }
        __syncthreads();   // B4

        // ---- P5: projection out[b,t,pn] = h @ W_lin[pn,:] + b_lin ----
        // (reads hb/wlf only; next P1 reads hb and writes actO -> no barrier)
        float p = 0.f;
        {
            F4H hu; hu.f4 = hb4[ps];
            F4H wu; wu.f4 = wlf[ps * 66 + pn];
            p = dot2(wu.h[0], hu.h[0], p);
            p = dot2(wu.h[1], hu.h[1], p);
            p = dot2(wu.h[2], hu.h[2], p);
            p = dot2(wu.h[3], hu.h[3], p);
        }
        p += __shfl_down(p, 8, 16);
        p += __shfl_down(p, 4, 16);
        p += __shfl_down(p, 2, 16);
        p += __shfl_down(p, 1, 16);
        if (ps == 0) orow[t * OO + pn] = p + bl;
    }
}

extern "C" void kernel_launch(void* const* d_in, const int* in_sizes, int n_in,
                              void* d_out, int out_size, void* d_ws, size_t ws_size,
                              hipStream_t stream) {
    (void)in_sizes; (void)n_in; (void)d_ws; (void)ws_size; (void)out_size;
    const float* x      = (const float*)d_in[0];
    const float* Wx_out = (const float*)d_in[1];
    const float* Wh_out = (const float*)d_in[2];
    const float* b_out  = (const float*)d_in[3];
    const float* Wx_in  = (const float*)d_in[4];
    const float* Wh_in  = (const float*)d_in[5];
    const float* b_in   = (const float*)d_in[6];
    const float* W_lin  = (const float*)d_in[7];
    const float* b_lin  = (const float*)d_in[8];
    float* out = (float*)d_out;

    nlstm_scan<<<dim3(BB), dim3(1024), 0, stream>>>(
        x, Wx_out, Wh_out, b_out, Wx_in, Wh_in, b_in, W_lin, b_lin, out);
}

// Round 5
// 9639.749 us; speedup vs baseline: 1.0395x; 1.0395x over previous
//
#include <hip/hip_runtime.h>
#include <hip/hip_fp16.h>

#define BB 128
#define II 64
#define SS 2048
#define HH 128
#define GG 512   // 4*H
#define OO 64

typedef _Float16 f16x2 __attribute__((ext_vector_type(2)));
union F4H { float4 f4; f16x2 h[4]; };

__device__ __forceinline__ f16x2 pack2(float a, float b) {
    f16x2 r; r.x = (_Float16)a; r.y = (_Float16)b; return r;
}
__device__ __forceinline__ float dot2(f16x2 w, f16x2 v, float c) {
    return __builtin_amdgcn_fdot2(w, v, c, false);
}
__device__ __forceinline__ float sigm(float v) {
    return __builtin_amdgcn_rcpf(1.0f + __expf(-v));
}
__device__ __forceinline__ float tanh_f(float v) {
    float a = fabsf(v);
    float e = __expf(-2.0f * a);
    float r = (1.0f - e) * __builtin_amdgcn_rcpf(1.0f + e);
    return v < 0.0f ? -r : r;
}

// One block per batch element, 1024 threads (16 waves). Lane pair (2k,2k+1)
// owns gate column k, K-split across the pair. Per-thread register weights:
// 32 (Wh_out half) + 64 (Wx_in or Wh_in) = 96 f16x2.
//
// VGPR-budget model from R1-R4 (the allocator ignores amdgpu_waves_per_eu;
// only launch_bounds' 2nd arg steers it, with a hidden 2x):
//   budget = 512 / (2 * min_waves_per_EU), default min = block_waves/4.
//   R1 (512,2)->128; R4 (1024,default=4)->64 (96 regs spilled -> 10 ms).
// So declare (1024, 2) -> budget 128 >= demand ~121..126. LDS 88 KB ->
// 1 block/CU -> real occupancy 16 waves (4/EU) regardless of the promise.
__global__ void __launch_bounds__(1024, 2)
nlstm_scan(
    const float* __restrict__ x,
    const float* __restrict__ Wx_out, const float* __restrict__ Wh_out,
    const float* __restrict__ b_out,
    const float* __restrict__ Wx_in, const float* __restrict__ Wh_in,
    const float* __restrict__ b_in,
    const float* __restrict__ W_lin, const float* __restrict__ b_lin,
    float* __restrict__ out)
{
    const int b   = blockIdx.x;
    const int j   = threadIdx.x;
    const int col = j >> 1;    // gate column 0..511
    const int s   = j & 1;     // K-split half within the lane pair

    // Wx_out fp16 chunk-major: chunk c (k=8c..8c+8) of column n at wxf[c*512+n]
    __shared__ __align__(16) float4 wxf[8 * 512];      // 64 KB
    // W_lin fp16 chunk-major padded: chunk c of row pn at wlf[c*66+pn]
    // (R2 geometry measured 0 bank conflicts; R4's pn=j>>4 variant hit 3.4e8)
    __shared__ __align__(16) float4 wlf[16 * 66];      // 16.9 KB
    __shared__ __align__(16) f16x2 xb[2][II / 2];      // x_t fp16, dbuf (8 chunks)
    __shared__ __align__(16) f16x2 hb[HH / 2];         // h fp16 (16 chunks)
    __shared__ __align__(16) f16x2 xih[HH];            // x_in (chunks 0-15) + h_in (16-31)
    __shared__ __align__(16) float cb[HH];             // outer cell fp32
    __shared__ __align__(16) float cnb[HH];            // inner cell fp32
    __shared__ __align__(16) float actO[GG];
    __shared__ __align__(16) float actI[GG];

    // ---- register-resident fp16 weights: 96 VGPRs/thread ----
    f16x2 who[32];   // Wh_out rows [64s, 64s+64) of column col
    f16x2 win[64];   // s==0: Wx_in col (all 128 rows); s==1: Wh_in col
    {
        const float* wp = Wh_out + (size_t)(64 * s) * GG + col;
#pragma unroll
        for (int m = 0; m < 32; ++m)
            who[m] = pack2(wp[(2 * m) * GG], wp[(2 * m + 1) * GG]);
        const float* vp = (s ? Wh_in : Wx_in) + col;
#pragma unroll
        for (int m = 0; m < 64; ++m)
            win[m] = pack2(vp[(2 * m) * GG], vp[(2 * m + 1) * GG]);
    }
    // Pin against rematerialization (demand fits the 128 budget now).
#pragma unroll
    for (int m = 0; m < 32; ++m) {
        float t0 = __builtin_bit_cast(float, who[m]);
        asm volatile("" : "+v"(t0));
        who[m] = __builtin_bit_cast(f16x2, t0);
    }
#pragma unroll
    for (int m = 0; m < 64; ++m) {
        float t0 = __builtin_bit_cast(float, win[m]);
        asm volatile("" : "+v"(t0));
        win[m] = __builtin_bit_cast(f16x2, t0);
    }

    const float bo = b_out[col];
    const float bi = b_in[col];
    const int   pn = j >> 3;                       // P5: output row (j<512)
    const int   ps = j & 7;                        // P5: k-slice
    const float bl = (j < 512) ? b_lin[pn] : 0.f;

    // ---- stage Wx_out -> LDS fp16 (setup only) ----
    {
        const int half = j >> 9, n = j & 511;
#pragma unroll
        for (int q = 0; q < 4; ++q) {
            const int c = 4 * half + q;
            F4H u;
#pragma unroll
            for (int r = 0; r < 4; ++r)
                u.h[r] = pack2(Wx_out[(8 * c + 2 * r) * GG + n],
                               Wx_out[(8 * c + 2 * r + 1) * GG + n]);
            wxf[c * 512 + n] = u.f4;
        }
    }
    // ---- stage W_lin -> LDS fp16 (1024 chunks, 1 per thread) ----
    {
        const int c = j >> 6, n = j & 63;
        F4H u;
#pragma unroll
        for (int r = 0; r < 4; ++r)
            u.h[r] = pack2(W_lin[n * HH + 8 * c + 2 * r],
                           W_lin[n * HH + 8 * c + 2 * r + 1]);
        wlf[c * 66 + n] = u.f4;
    }

    const float* xrow = x + (size_t)b * II * SS;   // x[b,i,t] = xrow[i*SS + t]
    float* orow = out + (size_t)b * SS * OO;

    if (j < HH / 2) hb[j] = pack2(0.f, 0.f);
    if (j < HH) { cb[j] = 0.f; cnb[j] = 0.f; }
    if (j < II / 2)  // stage x for t=0
        xb[0][j] = pack2(xrow[(2 * j) * SS], xrow[(2 * j + 1) * SS]);
    __syncthreads();

    const float4* hb4 = (const float4*)hb;               // 16 chunks
    const float4* vin = (const float4*)xih + 16 * s;     // my inner operand

#pragma unroll 1
    for (int t = 0; t < SS; ++t) {
        const float4* xb4 = (const float4*)xb[t & 1];    // 8 chunks

        // ---- P1: outer gates (half-K per lane) ----
        float acc = 0.f;
#pragma unroll
        for (int q = 0; q < 4; ++q) {                    // x part: chunks 4s+q
            F4H xu; xu.f4 = xb4[4 * s + q];
            F4H wu; wu.f4 = wxf[(4 * s + q) * 512 + col];
            acc = dot2(wu.h[0], xu.h[0], acc);
            acc = dot2(wu.h[1], xu.h[1], acc);
            acc = dot2(wu.h[2], xu.h[2], acc);
            acc = dot2(wu.h[3], xu.h[3], acc);
        }
#pragma unroll
        for (int q = 0; q < 8; ++q) {                    // h part: chunks 8s+q
            F4H hu; hu.f4 = hb4[8 * s + q];
            acc = dot2(who[4 * q + 0], hu.h[0], acc);
            acc = dot2(who[4 * q + 1], hu.h[1], acc);
            acc = dot2(who[4 * q + 2], hu.h[2], acc);
            acc = dot2(who[4 * q + 3], hu.h[3], acc);
        }
        {
            const float tot = acc + __shfl_xor(acc, 1, 64) + bo;
            const float v = (col < 384) ? sigm(tot) : tanh_f(tot);
            if (s == 0) actO[col] = v;   // even lane only: no same-addr pair store
        }
        __syncthreads();   // B1

        // ---- P2: form x_in / h_in; prefetch x for t+1 ----
        if (j < HH) {
            ((_Float16*)xih)[j] = (_Float16)(actO[j] * actO[384 + j]);       // x_in
        } else if (j < 2 * HH) {
            const int d = j - HH;
            ((_Float16*)xih)[HH + d] = (_Float16)(actO[HH + d] * cb[d]);     // h_in
        } else if (j >= 512 && j < 512 + II / 2 && t + 1 < SS) {
            const int m = j - 512;
            xb[(t + 1) & 1][m] = pack2(xrow[(2 * m) * SS + t + 1],
                                       xrow[(2 * m + 1) * SS + t + 1]);
        }
        __syncthreads();   // B2

        // ---- P3: inner gates (even lane: x_in@Wx_in, odd: h_in@Wh_in) ----
        float a2 = 0.f;
#pragma unroll
        for (int c = 0; c < 16; ++c) {
            F4H u; u.f4 = vin[c];
            a2 = dot2(win[4 * c + 0], u.h[0], a2);
            a2 = dot2(win[4 * c + 1], u.h[1], a2);
            a2 = dot2(win[4 * c + 2], u.h[2], a2);
            a2 = dot2(win[4 * c + 3], u.h[3], a2);
        }
        {
            const float tot = a2 + __shfl_xor(a2, 1, 64) + bi;
            const float v = (col < 384) ? sigm(tot) : tanh_f(tot);
            if (s == 0) actI[col] = v;
        }
        __syncthreads();   // B3

        // ---- P4: state update (threads 0..127) ----
        if (j < HH) {
            const float cn_new = actI[HH + j] * cnb[j] + actI[j] * actI[384 + j];
            const float c_new  = actI[2 * HH + j] * tanh_f(cn_new);
            const float h_new  = actO[2 * HH + j] * tanh_f(c_new);
            cnb[j] = cn_new;
            cb[j]  = c_new;
            ((_Float16*)hb)[j] = (_Float16)h_new;
        }
        __syncthreads();   // B4

        // ---- P5: projection (first 512 threads, R2 geometry: 0 conflicts) ----
        if (j < 512) {
            float p = 0.f;
#pragma unroll
            for (int q = 0; q < 2; ++q) {
                const int c = 2 * ps + q;
                F4H hu; hu.f4 = hb4[c];
                F4H wu; wu.f4 = wlf[c * 66 + pn];
                p = dot2(wu.h[0], hu.h[0], p);
                p = dot2(wu.h[1], hu.h[1], p);
                p = dot2(wu.h[2], hu.h[2], p);
                p = dot2(wu.h[3], hu.h[3], p);
            }
            p += __shfl_down(p, 4, 8);
            p += __shfl_down(p, 2, 8);
            p += __shfl_down(p, 1, 8);
            if (ps == 0) orow[t * OO + pn] = p + bl;
        }
    }
}

extern "C" void kernel_launch(void* const* d_in, const int* in_sizes, int n_in,
                              void* d_out, int out_size, void* d_ws, size_t ws_size,
                              hipStream_t stream) {
    (void)in_sizes; (void)n_in; (void)d_ws; (void)ws_size; (void)out_size;
    const float* x      = (const float*)d_in[0];
    const float* Wx_out = (const float*)d_in[1];
    const float* Wh_out = (const float*)d_in[2];
    const float* b_out  = (const float*)d_in[3];
    const float* Wx_in  = (const float*)d_in[4];
    const float* Wh_in  = (const float*)d_in[5];
    const float* b_in   = (const float*)d_in[6];
    const float* W_lin  = (const float*)d_in[7];
    const float* b_lin  = (const float*)d_in[8];
    float* out = (float*)d_out;

    nlstm_scan<<<dim3(BB), dim3(1024), 0, stream>>>(
        x, Wx_out, Wh_out, b_out, Wx_in, Wh_in, b_in, W_lin, b_lin, out);
}